// Round 1
// baseline (91.992 us; speedup 1.0000x reference)
//
#include <hip/hip_runtime.h>

#define COLS   8192
#define LEVELS 8
#define TPB    256

// One block per row. Whole 8-level analysis + synthesis in LDS.
// A: current/next approx ping-pong (with B). C: all detail coeffs + final approx.
__global__ __launch_bounds__(TPB) void despawn_kernel(
    const float* __restrict__ x, const float* __restrict__ scaling,
    float* __restrict__ out, int rows)
{
    __shared__ float A[COLS];          // 32 KB
    __shared__ float B[COLS / 2];      // 16 KB
    __shared__ float C[COLS];          // 32 KB: details lev0..7 then final approx
    __shared__ float filt[LEVELS * 4];

    const int row = blockIdx.x;
    const int tid = threadIdx.x;

    if (tid < LEVELS * 4) filt[tid] = scaling[tid];

    // coalesced float4 row load
    const float4* __restrict__ xin =
        reinterpret_cast<const float4*>(x + (size_t)row * COLS);
    float4* As4 = reinterpret_cast<float4*>(A);
    for (int i = tid; i < COLS / 4; i += TPB) As4[i] = xin[i];
    __syncthreads();

    float* __restrict__ out_rec  = out + (size_t)row * COLS;
    float* __restrict__ out_coef = out + (size_t)rows * COLS + (size_t)row * COLS;

    // ---------------- analysis ----------------
    int n = COLS, coff = 0;
    float* cur = A;
    float* nxt = B;
    for (int lev = 0; lev < LEVELS; ++lev) {
        const float h0 = filt[4 * lev + 0], h1 = filt[4 * lev + 1],
                    h2 = filt[4 * lev + 2], h3 = filt[4 * lev + 3];
        const float g0 = h3, g1 = -h2, g2 = h1, g3 = -h0;
        const int half = n >> 1, mask = n - 1;
        for (int i = tid; i < half; i += TPB) {
            const int b = 2 * i;
            const float x0 = cur[b];
            const float x1 = cur[(b - 1) & mask];
            const float x2 = cur[(b - 2) & mask];
            const float x3 = cur[(b - 3) & mask];
            const float d = g0 * x0 + g1 * x1 + g2 * x2 + g3 * x3;
            const float a = h0 * x0 + h1 * x1 + h2 * x2 + h3 * x3;
            C[coff + i] = d;
            out_coef[coff + i] = d;   // detail coeffs straight to global
            nxt[i] = a;
        }
        __syncthreads();
        coff += half;
        n = half;
        float* t = cur; cur = nxt; nxt = t;
    }
    // final approx (length n == COLS>>LEVELS) sits in `cur`
    for (int i = tid; i < n; i += TPB) {
        const float a = cur[i];
        C[coff + i] = a;
        out_coef[coff + i] = a;
    }
    __syncthreads();

    // ---------------- synthesis ----------------
    // rec[2j]   = g0*d[j]   + g2*d[j+1] + h0*a[j]   + h2*a[j+1]
    // rec[2j+1] = g1*d[j+1] + g3*d[j+2] + h1*a[j+1] + h3*a[j+2]   (mod m)
    int m = COLS >> LEVELS;                 // 32
    const float* aprev = C + (COLS - m);    // final approx
    int doff = COLS - 2 * m;                // detail offset of level LEVELS-1
    for (int lev = LEVELS - 1; lev >= 0; --lev) {
        const float h0 = filt[4 * lev + 0], h1 = filt[4 * lev + 1],
                    h2 = filt[4 * lev + 2], h3 = filt[4 * lev + 3];
        const float g0 = h3, g1 = -h2, g2 = h1, g3 = -h0;
        const float* d = C + doff;
        const int mm = m - 1;
        float* rec = (lev & 1) ? B : A;     // lev7->B(64) ... lev1->B(4096); lev0 -> global
        const bool last = (lev == 0);
        for (int j = tid; j < m; j += TPB) {
            const float dj  = d[j];
            const float dj1 = d[(j + 1) & mm];
            const float dj2 = d[(j + 2) & mm];
            const float aj  = aprev[j];
            const float aj1 = aprev[(j + 1) & mm];
            const float aj2 = aprev[(j + 2) & mm];
            const float r0 = g0 * dj  + g2 * dj1 + h0 * aj  + h2 * aj1;
            const float r1 = g1 * dj1 + g3 * dj2 + h1 * aj1 + h3 * aj2;
            if (last) {
                reinterpret_cast<float2*>(out_rec)[j] = make_float2(r0, r1);
            } else {
                rec[2 * j]     = r0;
                rec[2 * j + 1] = r1;
            }
        }
        __syncthreads();
        aprev = rec;
        m <<= 1;
        doff -= m;
    }
}

extern "C" void kernel_launch(void* const* d_in, const int* in_sizes, int n_in,
                              void* d_out, int out_size, void* d_ws, size_t ws_size,
                              hipStream_t stream) {
    const float* x       = (const float*)d_in[0];
    const float* scaling = (const float*)d_in[1];
    float* out           = (float*)d_out;
    const int rows = in_sizes[0] / COLS;
    despawn_kernel<<<rows, TPB, 0, stream>>>(x, scaling, out, rows);
}

// Round 2
// 66.503 us; speedup vs baseline: 1.3833x; 1.3833x over previous
//
#include <hip/hip_runtime.h>

#define COLS   8192
#define LEVELS 8
#define TPB    256

// One block per row. 8-level analysis + synthesis.
// LDS: A (32 KB) + B (16 KB) approx ping-pong only -> 3 blocks/CU.
// Detail coeffs stream to global during analysis and are re-read (L2-hot)
// during synthesis.
__global__ __launch_bounds__(TPB) void despawn_kernel(
    const float* __restrict__ x, const float* __restrict__ scaling,
    float* __restrict__ out, int rows)
{
    __shared__ float A[COLS];          // 32 KB
    __shared__ float B[COLS / 2];      // 16 KB
    __shared__ float filt[LEVELS * 4];

    const int row = blockIdx.x;
    const int tid = threadIdx.x;

    if (tid < LEVELS * 4) filt[tid] = scaling[tid];

    // coalesced float4 row load
    const float4* __restrict__ xin =
        reinterpret_cast<const float4*>(x + (size_t)row * COLS);
    float4* As4 = reinterpret_cast<float4*>(A);
    for (int i = tid; i < COLS / 4; i += TPB) As4[i] = xin[i];
    __syncthreads();

    float* __restrict__ out_rec  = out + (size_t)row * COLS;
    float* __restrict__ out_coef = out + (size_t)rows * COLS + (size_t)row * COLS;

    // ---------------- analysis ----------------
    // d[i] = g0*a[2i] + g1*a[2i-1] + g2*a[2i-2] + g3*a[2i-3]   (mod n)
    // a'[i]= h0*a[2i] + h1*a[2i-1] + h2*a[2i-2] + h3*a[2i-3]
    int n = COLS, coff = 0;
    float* cur = A;
    float* nxt = B;
    for (int lev = 0; lev < LEVELS; ++lev) {
        const float h0 = filt[4 * lev + 0], h1 = filt[4 * lev + 1],
                    h2 = filt[4 * lev + 2], h3 = filt[4 * lev + 3];
        const float g0 = h3, g1 = -h2, g2 = h1, g3 = -h0;
        const int half = n >> 1, mask = n - 1;
        for (int i = tid; i < half; i += TPB) {
            const int b = 2 * i;
            const float x0 = cur[b];
            const float x1 = cur[(b - 1) & mask];
            const float x2 = cur[(b - 2) & mask];
            const float x3 = cur[(b - 3) & mask];
            out_coef[coff + i] = g0 * x0 + g1 * x1 + g2 * x2 + g3 * x3;
            nxt[i]            = h0 * x0 + h1 * x1 + h2 * x2 + h3 * x3;
        }
        __syncthreads();
        coff += half;
        n = half;
        float* t = cur; cur = nxt; nxt = t;
    }
    // final approx (length 32) sits in cur == A
    for (int i = tid; i < n; i += TPB) out_coef[coff + i] = cur[i];
    __syncthreads();

    // ---------------- synthesis ----------------
    // rec[2j]   = g0*d[j]   + g2*d[j+1] + h0*a[j]   + h2*a[j+1]
    // rec[2j+1] = g1*d[j+1] + g3*d[j+2] + h1*a[j+1] + h3*a[j+2]   (mod m)
    int m = COLS >> LEVELS;                 // 32
    const float* aprevL = A;                // final approx in LDS A[0..31]
    int doff = COLS - 2 * m;                // 8128: detail offset of level 7
    for (int lev = LEVELS - 1; lev >= 0; --lev) {
        const float h0 = filt[4 * lev + 0], h1 = filt[4 * lev + 1],
                    h2 = filt[4 * lev + 2], h3 = filt[4 * lev + 3];
        const float g0 = h3, g1 = -h2, g2 = h1, g3 = -h0;
        const float* __restrict__ d = out_coef + doff;  // L2-hot re-read
        const int mm = m - 1;
        float* rec = (lev & 1) ? B : A;     // lev7->B(64) ... lev1->B(4096)
        const bool last = (lev == 0);
        for (int j = tid; j < m; j += TPB) {
            const float dj  = d[j];
            const float dj1 = d[(j + 1) & mm];
            const float dj2 = d[(j + 2) & mm];
            const float aj  = aprevL[j];
            const float aj1 = aprevL[(j + 1) & mm];
            const float aj2 = aprevL[(j + 2) & mm];
            const float r0 = g0 * dj  + g2 * dj1 + h0 * aj  + h2 * aj1;
            const float r1 = g1 * dj1 + g3 * dj2 + h1 * aj1 + h3 * aj2;
            if (last) {
                reinterpret_cast<float2*>(out_rec)[j] = make_float2(r0, r1);
            } else {
                reinterpret_cast<float2*>(rec)[j] = make_float2(r0, r1);
            }
        }
        __syncthreads();
        aprevL = rec;
        m <<= 1;
        doff -= m;
    }
}

extern "C" void kernel_launch(void* const* d_in, const int* in_sizes, int n_in,
                              void* d_out, int out_size, void* d_ws, size_t ws_size,
                              hipStream_t stream) {
    const float* x       = (const float*)d_in[0];
    const float* scaling = (const float*)d_in[1];
    float* out           = (float*)d_out;
    const int rows = in_sizes[0] / COLS;
    despawn_kernel<<<rows, TPB, 0, stream>>>(x, scaling, out, rows);
}

// Round 3
// 63.148 us; speedup vs baseline: 1.4568x; 1.0531x over previous
//
#include <hip/hip_runtime.h>

#define COLS   8192
#define LEVELS 8
#define TPB    256

// One block per row. LDS holds only the shrinking approx ping-pong:
// B (16 KB) + C (8 KB) -> ~24.7 KB/block -> 6 blocks/CU.
// Level-0 analysis reads x straight from global (L1-cached overlapping loads);
// detail coeffs stream to global and are re-read (L2-hot) during synthesis.
__global__ __launch_bounds__(TPB) void despawn_kernel(
    const float* __restrict__ x, const float* __restrict__ scaling,
    float* __restrict__ out, int rows)
{
    __shared__ float B[COLS / 2];      // 16 KB
    __shared__ float C[COLS / 4];      // 8 KB
    __shared__ float filt[LEVELS * 4];

    const int row = blockIdx.x;
    const int tid = threadIdx.x;

    if (tid < LEVELS * 4) filt[tid] = scaling[tid];
    __syncthreads();

    const float* __restrict__ xg       = x + (size_t)row * COLS;
    float* __restrict__       out_rec  = out + (size_t)row * COLS;
    float* __restrict__       out_coef = out + (size_t)rows * COLS + (size_t)row * COLS;

    // ---------------- analysis level 0 (from global) ----------------
    // d[i] = g0*x[2i] + g1*x[2i-1] + g2*x[2i-2] + g3*x[2i-3]   (mod 8192)
    {
        const float h0 = filt[0], h1 = filt[1], h2 = filt[2], h3 = filt[3];
        const float g0 = h3, g1 = -h2, g2 = h1, g3 = -h0;
        const float2* __restrict__ xg2 = reinterpret_cast<const float2*>(xg);
        const int half = COLS / 2, m2 = half - 1;
        for (int i = tid; i < half; i += TPB) {
            const float2 vb = xg2[i];              // x[2i],   x[2i+1]
            const float2 va = xg2[(i - 1) & m2];   // x[2i-2], x[2i-1]
            const float2 vc = xg2[(i - 2) & m2];   // x[2i-4], x[2i-3]
            const float x0 = vb.x, x1 = va.y, x2 = va.x, x3 = vc.y;
            out_coef[i] = g0 * x0 + g1 * x1 + g2 * x2 + g3 * x3;
            B[i]        = h0 * x0 + h1 * x1 + h2 * x2 + h3 * x3;
        }
        __syncthreads();
    }

    // ---------------- analysis levels 1..7 (LDS ping-pong) ----------------
    int n = COLS / 2, coff = COLS / 2;
    float* cur = B;
    float* nxt = C;
    for (int lev = 1; lev < LEVELS; ++lev) {
        const float h0 = filt[4 * lev + 0], h1 = filt[4 * lev + 1],
                    h2 = filt[4 * lev + 2], h3 = filt[4 * lev + 3];
        const float g0 = h3, g1 = -h2, g2 = h1, g3 = -h0;
        const int half = n >> 1, mask = n - 1;
        const bool lastlev = (lev == LEVELS - 1);
        for (int i = tid; i < half; i += TPB) {
            const int b = 2 * i;
            const float x0 = cur[b];
            const float x1 = cur[(b - 1) & mask];
            const float x2 = cur[(b - 2) & mask];
            const float x3 = cur[(b - 3) & mask];
            const float a = h0 * x0 + h1 * x1 + h2 * x2 + h3 * x3;
            out_coef[coff + i] = g0 * x0 + g1 * x1 + g2 * x2 + g3 * x3;
            nxt[i] = a;
            if (lastlev) out_coef[coff + half + i] = a;  // final approx
        }
        __syncthreads();
        coff += half;
        n = half;
        float* t = cur; cur = nxt; nxt = t;
    }
    // final approx (32) now in cur == C

    // ---------------- synthesis ----------------
    // rec[2j]   = g0*d[j]   + g2*d[j+1] + h0*a[j]   + h2*a[j+1]
    // rec[2j+1] = g1*d[j+1] + g3*d[j+2] + h1*a[j+1] + h3*a[j+2]   (mod m)
    int m = COLS >> LEVELS;                 // 32
    const float* aprev = cur;               // C
    int doff = COLS - 2 * m;                // 8128
    for (int lev = LEVELS - 1; lev >= 0; --lev) {
        const float h0 = filt[4 * lev + 0], h1 = filt[4 * lev + 1],
                    h2 = filt[4 * lev + 2], h3 = filt[4 * lev + 3];
        const float g0 = h3, g1 = -h2, g2 = h1, g3 = -h0;
        const float* __restrict__ d = out_coef + doff;  // L2-hot re-read
        const int mm = m - 1;
        // lev7->B(64) lev6->C(128) lev5->B lev4->C lev3->B lev2->C(2048) lev1->B(4096)
        float* rec = (lev & 1) ? B : C;
        const bool last = (lev == 0);
        for (int j = tid; j < m; j += TPB) {
            const float dj  = d[j];
            const float dj1 = d[(j + 1) & mm];
            const float dj2 = d[(j + 2) & mm];
            const float aj  = aprev[j];
            const float aj1 = aprev[(j + 1) & mm];
            const float aj2 = aprev[(j + 2) & mm];
            const float r0 = g0 * dj  + g2 * dj1 + h0 * aj  + h2 * aj1;
            const float r1 = g1 * dj1 + g3 * dj2 + h1 * aj1 + h3 * aj2;
            if (last) {
                reinterpret_cast<float2*>(out_rec)[j] = make_float2(r0, r1);
            } else {
                reinterpret_cast<float2*>(rec)[j] = make_float2(r0, r1);
            }
        }
        __syncthreads();
        aprev = rec;
        m <<= 1;
        doff -= m;
    }
}

extern "C" void kernel_launch(void* const* d_in, const int* in_sizes, int n_in,
                              void* d_out, int out_size, void* d_ws, size_t ws_size,
                              hipStream_t stream) {
    const float* x       = (const float*)d_in[0];
    const float* scaling = (const float*)d_in[1];
    float* out           = (float*)d_out;
    const int rows = in_sizes[0] / COLS;
    despawn_kernel<<<rows, TPB, 0, stream>>>(x, scaling, out, rows);
}

// Round 4
// 44.796 us; speedup vs baseline: 2.0536x; 1.4097x over previous
//
#include <hip/hip_runtime.h>

#define COLS   8192
#define LEVELS 8
#define TPB    512

// One block per row. LDS holds only the shrinking approx ping-pong:
// B (16 KB) + C (8 KB) -> ~24.7 KB/block; TPB=512 -> 4 blocks/CU = 32 waves/CU.
// Level-0 analysis reads x straight from global (float4); detail coeffs stream
// to global and are re-read (L2-hot) during synthesis. All phases vectorized.
__global__ __launch_bounds__(TPB) void despawn_kernel(
    const float* __restrict__ x, const float* __restrict__ scaling,
    float* __restrict__ out, int rows)
{
    __shared__ __align__(16) float B[COLS / 2];   // 16 KB
    __shared__ __align__(16) float C[COLS / 4];   // 8 KB
    __shared__ float filt[LEVELS * 4];

    const int row = blockIdx.x;
    const int tid = threadIdx.x;

    if (tid < LEVELS * 4) filt[tid] = scaling[tid];
    __syncthreads();

    const float* __restrict__ xg       = x + (size_t)row * COLS;
    float* __restrict__       out_rec  = out + (size_t)row * COLS;
    float* __restrict__       out_coef = out + (size_t)rows * COLS + (size_t)row * COLS;

    // ---------------- analysis level 0 (global float4, 2 outputs/thread) ----
    // d[k] = g0*x[2k] + g1*x[2k-1] + g2*x[2k-2] + g3*x[2k-3]   (mod 8192)
    {
        const float h0 = filt[0], h1 = filt[1], h2 = filt[2], h3 = filt[3];
        const float g0 = h3, g1 = -h2, g2 = h1, g3 = -h0;
        const float4* __restrict__ xg4 = reinterpret_cast<const float4*>(xg);
        const int q = COLS / 4, qm = q - 1;
        for (int i = tid; i < q; i += TPB) {
            const float4 vb = xg4[i];             // x[4i..4i+3]
            const float4 va = xg4[(i - 1) & qm];  // x[4i-4..4i-1]
            const float d0 = g0*vb.x + g1*va.w + g2*va.z + g3*va.y;  // k=2i
            const float a0 = h0*vb.x + h1*va.w + h2*va.z + h3*va.y;
            const float d1 = g0*vb.z + g1*vb.y + g2*vb.x + g3*va.w;  // k=2i+1
            const float a1 = h0*vb.z + h1*vb.y + h2*vb.x + h3*va.w;
            reinterpret_cast<float2*>(out_coef)[i] = make_float2(d0, d1);
            reinterpret_cast<float2*>(B)[i]        = make_float2(a0, a1);
        }
        __syncthreads();
    }

    // ---------------- analysis levels 1..7 (ds_read_b128, 2 outputs/thread) --
    int n = COLS / 2, coff = COLS / 2;
    float* cur = B;
    float* nxt = C;
    for (int lev = 1; lev < LEVELS; ++lev) {
        const float h0 = filt[4*lev+0], h1 = filt[4*lev+1],
                    h2 = filt[4*lev+2], h3 = filt[4*lev+3];
        const float g0 = h3, g1 = -h2, g2 = h1, g3 = -h0;
        const int half = n >> 1;
        const int hq = half >> 1, hm = hq - 1;    // output pairs
        const bool lastlev = (lev == LEVELS - 1);
        const float4* c4 = reinterpret_cast<const float4*>(cur);
        for (int p = tid; p < hq; p += TPB) {
            const float4 vb = c4[p];              // cur[4p..4p+3]
            const float4 va = c4[(p - 1) & hm];   // cur[4p-4..4p-1]
            const float d0 = g0*vb.x + g1*va.w + g2*va.z + g3*va.y;  // k=2p
            const float a0 = h0*vb.x + h1*va.w + h2*va.z + h3*va.y;
            const float d1 = g0*vb.z + g1*vb.y + g2*vb.x + g3*va.w;  // k=2p+1
            const float a1 = h0*vb.z + h1*vb.y + h2*vb.x + h3*va.w;
            reinterpret_cast<float2*>(out_coef + coff)[p] = make_float2(d0, d1);
            reinterpret_cast<float2*>(nxt)[p]             = make_float2(a0, a1);
            if (lastlev)  // final approx
                reinterpret_cast<float2*>(out_coef + coff + half)[p] = make_float2(a0, a1);
        }
        __syncthreads();
        coff += half;
        n = half;
        float* t = cur; cur = nxt; nxt = t;
    }
    // final approx (32) now in cur == C

    // ---------------- synthesis (4 outputs/thread, float4 stores) -----------
    // rec[2j]   = g0*d[j]   + g2*d[j+1] + h0*a[j]   + h2*a[j+1]
    // rec[2j+1] = g1*d[j+1] + g3*d[j+2] + h1*a[j+1] + h3*a[j+2]   (mod m)
    int m = COLS >> LEVELS;                 // 32
    const float* aprev = cur;               // C
    int doff = COLS - 2 * m;                // 8128
    for (int lev = LEVELS - 1; lev >= 0; --lev) {
        const float h0 = filt[4*lev+0], h1 = filt[4*lev+1],
                    h2 = filt[4*lev+2], h3 = filt[4*lev+3];
        const float g0 = h3, g1 = -h2, g2 = h1, g3 = -h0;
        const float2* __restrict__ d2 = reinterpret_cast<const float2*>(out_coef + doff);
        const float2* a2 = reinterpret_cast<const float2*>(aprev);
        const int mp = m >> 1, mm = mp - 1;
        float* rec = (lev & 1) ? B : C;     // lev7->B(64) ... lev1->B(4096)
        const bool last = (lev == 0);
        for (int p = tid; p < mp; p += TPB) {
            const float2 dv0 = d2[p];               // d[2p],   d[2p+1]
            const float2 dv1 = d2[(p + 1) & mm];    // d[2p+2], d[2p+3]
            const float2 av0 = a2[p];
            const float2 av1 = a2[(p + 1) & mm];
            const float r0 = g0*dv0.x + g2*dv0.y + h0*av0.x + h2*av0.y;  // rec[4p]
            const float r1 = g1*dv0.y + g3*dv1.x + h1*av0.y + h3*av1.x;  // rec[4p+1]
            const float r2 = g0*dv0.y + g2*dv1.x + h0*av0.y + h2*av1.x;  // rec[4p+2]
            const float r3 = g1*dv1.x + g3*dv1.y + h1*av1.x + h3*av1.y;  // rec[4p+3]
            if (last)
                reinterpret_cast<float4*>(out_rec)[p] = make_float4(r0, r1, r2, r3);
            else
                reinterpret_cast<float4*>(rec)[p]     = make_float4(r0, r1, r2, r3);
        }
        __syncthreads();
        aprev = rec;
        m <<= 1;
        doff -= m;
    }
}

extern "C" void kernel_launch(void* const* d_in, const int* in_sizes, int n_in,
                              void* d_out, int out_size, void* d_ws, size_t ws_size,
                              hipStream_t stream) {
    const float* x       = (const float*)d_in[0];
    const float* scaling = (const float*)d_in[1];
    float* out           = (float*)d_out;
    const int rows = in_sizes[0] / COLS;
    despawn_kernel<<<rows, TPB, 0, stream>>>(x, scaling, out, rows);
}

// Round 5
// 42.797 us; speedup vs baseline: 2.1495x; 1.0467x over previous
//
#include <hip/hip_runtime.h>

#define COLS   8192
#define LEVELS 8
#define TPB    512

// One block per row.
// LDS: B(16K) + C(8K) approx ping-pong, D(8K) = details lev2..7 + final approx.
// Analysis lev0 reads x from global (float4); details lev0/1 go to global only
// (synthesis re-reads them L2-hot with high parallelism); details lev2..7 also
// kept in D so the latency-bound tail never touches global.
// Levels 4..7 (both directions) run on wave 0 only: in-wave LDS ordering,
// no block barriers.
__global__ __launch_bounds__(TPB) void despawn_kernel(
    const float* __restrict__ x, const float* __restrict__ scaling,
    float* __restrict__ out, int rows)
{
    __shared__ __align__(16) float B[COLS / 2];   // 16 KB
    __shared__ __align__(16) float C[COLS / 4];   // 8 KB
    __shared__ __align__(16) float D[COLS / 4];   // 8 KB
    __shared__ float filt[LEVELS * 4];

    const int row = blockIdx.x;
    const int tid = threadIdx.x;

    if (tid < LEVELS * 4) filt[tid] = scaling[tid];
    __syncthreads();

    const float* __restrict__ xg       = x + (size_t)row * COLS;
    float* __restrict__       out_rec  = out + (size_t)row * COLS;
    float* __restrict__       out_coef = out + (size_t)rows * COLS + (size_t)row * COLS;

    // ---------------- analysis level 0 (global float4, 4 outputs/thread) ----
    // d[k] = g0*x[2k] + g1*x[2k-1] + g2*x[2k-2] + g3*x[2k-3]   (mod 8192)
    {
        const float h0 = filt[0], h1 = filt[1], h2 = filt[2], h3 = filt[3];
        const float g0 = h3, g1 = -h2, g2 = h1, g3 = -h0;
        const float4* __restrict__ xg4 = reinterpret_cast<const float4*>(xg);
        const int q8 = COLS / 8, qm = COLS / 4 - 1;
        for (int i = tid; i < q8; i += TPB) {
            const float4 va = xg4[(2 * i - 1) & qm];   // x[8i-4..8i-1]
            const float4 vb = xg4[2 * i];              // x[8i  ..8i+3]
            const float4 vc = xg4[2 * i + 1];          // x[8i+4..8i+7]
            float4 dv, av;
            dv.x = g0*vb.x + g1*va.w + g2*va.z + g3*va.y;
            av.x = h0*vb.x + h1*va.w + h2*va.z + h3*va.y;
            dv.y = g0*vb.z + g1*vb.y + g2*vb.x + g3*va.w;
            av.y = h0*vb.z + h1*vb.y + h2*vb.x + h3*va.w;
            dv.z = g0*vc.x + g1*vb.w + g2*vb.z + g3*vb.y;
            av.z = h0*vc.x + h1*vb.w + h2*vb.z + h3*vb.y;
            dv.w = g0*vc.z + g1*vc.y + g2*vc.x + g3*vb.w;
            av.w = h0*vc.z + h1*vc.y + h2*vc.x + h3*vb.w;
            reinterpret_cast<float4*>(out_coef)[i] = dv;
            reinterpret_cast<float4*>(B)[i]        = av;
        }
        __syncthreads();
    }

    // ---------------- analysis levels 1..3 (LDS float4, 4 outputs/thread) ---
    int n = COLS / 2, coff = COLS / 2, dOff = 0;
    float* cur = B;
    float* nxt = C;
    for (int lev = 1; lev <= 3; ++lev) {
        const float h0 = filt[4*lev+0], h1 = filt[4*lev+1],
                    h2 = filt[4*lev+2], h3 = filt[4*lev+3];
        const float g0 = h3, g1 = -h2, g2 = h1, g3 = -h0;
        const int half = n >> 1, qq = half >> 2, qm = (n >> 2) - 1;
        const float4* c4 = reinterpret_cast<const float4*>(cur);
        float4* o4 = reinterpret_cast<float4*>(out_coef + coff);
        float4* n4 = reinterpret_cast<float4*>(nxt);
        float4* D4 = reinterpret_cast<float4*>(D + dOff);
        const bool toD = (lev >= 2);
        for (int p = tid; p < qq; p += TPB) {
            const float4 va = c4[(2 * p - 1) & qm];
            const float4 vb = c4[2 * p];
            const float4 vc = c4[2 * p + 1];
            float4 dv, av;
            dv.x = g0*vb.x + g1*va.w + g2*va.z + g3*va.y;
            av.x = h0*vb.x + h1*va.w + h2*va.z + h3*va.y;
            dv.y = g0*vb.z + g1*vb.y + g2*vb.x + g3*va.w;
            av.y = h0*vb.z + h1*vb.y + h2*vb.x + h3*va.w;
            dv.z = g0*vc.x + g1*vb.w + g2*vb.z + g3*vb.y;
            av.z = h0*vc.x + h1*vb.w + h2*vb.z + h3*vb.y;
            dv.w = g0*vc.z + g1*vc.y + g2*vc.x + g3*vb.w;
            av.w = h0*vc.z + h1*vc.y + h2*vc.x + h3*vb.w;
            o4[p] = dv;
            n4[p] = av;
            if (toD) D4[p] = dv;
        }
        __syncthreads();
        coff += half;
        if (toD) dOff += half;
        n = half;
        float* t = cur; cur = nxt; nxt = t;
    }
    // approx(512) now in C (cur == C)

    // ---------------- wave-0 tail: levels 4..7 both directions --------------
    // D layout: lev2@0(1024) lev3@1024(512) lev4@1536(256) lev5@1792(128)
    //           lev6@1920(64) lev7@1984(32) approx@2016(32)
    if (tid < 64) {
        float* acur = C;
        float* anxt = B;
        int nn = 512, coffW = 7680, dW = 1536;
        for (int lev = 4; lev <= 7; ++lev) {
            const float h0 = filt[4*lev+0], h1 = filt[4*lev+1],
                        h2 = filt[4*lev+2], h3 = filt[4*lev+3];
            const float g0 = h3, g1 = -h2, g2 = h1, g3 = -h0;
            const int half = nn >> 1, mask = nn - 1;
            for (int i = tid; i < half; i += 64) {
                const int b = 2 * i;
                const float x0 = acur[b];
                const float x1 = acur[(b - 1) & mask];
                const float x2 = acur[(b - 2) & mask];
                const float x3 = acur[(b - 3) & mask];
                const float d = g0*x0 + g1*x1 + g2*x2 + g3*x3;
                const float a = h0*x0 + h1*x1 + h2*x2 + h3*x3;
                D[dW + i] = d;
                out_coef[coffW + i] = d;
                if (lev == 7) { D[2016 + i] = a; out_coef[8160 + i] = a; }
                else          anxt[i] = a;
            }
            __builtin_amdgcn_wave_barrier();
            coffW += half; dW += half; nn = half;
            float* t = acur; acur = anxt; anxt = t;
        }
        // synthesis lev7..4 (in-wave)
        int mS = 32, dS = 1984;
        const float* aprevW = D + 2016;
        for (int lev = 7; lev >= 4; --lev) {
            const float h0 = filt[4*lev+0], h1 = filt[4*lev+1],
                        h2 = filt[4*lev+2], h3 = filt[4*lev+3];
            const float g0 = h3, g1 = -h2, g2 = h1, g3 = -h0;
            const int mm = mS - 1;
            float* recW = (lev & 1) ? B : C;
            for (int j = tid; j < mS; j += 64) {
                const float dj  = D[dS + j];
                const float dj1 = D[dS + ((j + 1) & mm)];
                const float dj2 = D[dS + ((j + 2) & mm)];
                const float aj  = aprevW[j];
                const float aj1 = aprevW[(j + 1) & mm];
                const float aj2 = aprevW[(j + 2) & mm];
                recW[2*j]     = g0*dj  + g2*dj1 + h0*aj  + h2*aj1;
                recW[2*j + 1] = g1*dj1 + g3*dj2 + h1*aj1 + h3*aj2;
            }
            __builtin_amdgcn_wave_barrier();
            aprevW = recW; mS <<= 1; dS -= mS;
        }
    }
    __syncthreads();
    // lev4 rec (512) now in C

    // ---------------- synthesis levels 3..0 (all threads, 4 out/thread) -----
    // rec[2j]   = g0*d[j]   + g2*d[j+1] + h0*a[j]   + h2*a[j+1]
    // rec[2j+1] = g1*d[j+1] + g3*d[j+2] + h1*a[j+1] + h3*a[j+2]   (mod m)
#define SYNTH_BODY(d2)                                                        \
    for (int p = tid; p < mp; p += TPB) {                                     \
        const float2 dv0 = (d2)[p];                                           \
        const float2 dv1 = (d2)[(p + 1) & mm];                                \
        const float2 av0 = a2[p];                                             \
        const float2 av1 = a2[(p + 1) & mm];                                  \
        const float r0 = g0*dv0.x + g2*dv0.y + h0*av0.x + h2*av0.y;           \
        const float r1 = g1*dv0.y + g3*dv1.x + h1*av0.y + h3*av1.x;           \
        const float r2 = g0*dv0.y + g2*dv1.x + h0*av0.y + h2*av1.x;           \
        const float r3 = g1*dv1.x + g3*dv1.y + h1*av1.x + h3*av1.y;           \
        const float4 rv = make_float4(r0, r1, r2, r3);                        \
        if (last) reinterpret_cast<float4*>(out_rec)[p] = rv;                 \
        else      reinterpret_cast<float4*>(rec)[p]     = rv;                 \
    }

    const float* aprev = C;
    int m = 512;
    for (int lev = 3; lev >= 0; --lev) {
        const float h0 = filt[4*lev+0], h1 = filt[4*lev+1],
                    h2 = filt[4*lev+2], h3 = filt[4*lev+3];
        const float g0 = h3, g1 = -h2, g2 = h1, g3 = -h0;
        const int mp = m >> 1, mm = mp - 1;
        const float2* a2 = reinterpret_cast<const float2*>(aprev);
        float* rec = (lev & 1) ? B : C;   // lev3->B lev2->C lev1->B
        const bool last = (lev == 0);
        if (lev >= 2) {
            const float2* dL = reinterpret_cast<const float2*>(D + ((lev == 3) ? 1024 : 0));
            SYNTH_BODY(dL)
        } else {
            const float2* __restrict__ dG =
                reinterpret_cast<const float2*>(out_coef + ((lev == 1) ? 4096 : 0));
            SYNTH_BODY(dG)
        }
        if (lev) __syncthreads();
        aprev = rec; m <<= 1;
    }
#undef SYNTH_BODY
}

extern "C" void kernel_launch(void* const* d_in, const int* in_sizes, int n_in,
                              void* d_out, int out_size, void* d_ws, size_t ws_size,
                              hipStream_t stream) {
    const float* x       = (const float*)d_in[0];
    const float* scaling = (const float*)d_in[1];
    float* out           = (float*)d_out;
    const int rows = in_sizes[0] / COLS;
    despawn_kernel<<<rows, TPB, 0, stream>>>(x, scaling, out, rows);
}